// Round 1
// baseline (745.360 us; speedup 1.0000x reference)
//
#include <hip/hip_runtime.h>

// ---------------------------------------------------------------------------
// SingleHeadAttention: out = softmax(mask((q Wq^T)(k Wk^T)^T / 16)) (v Wv^T)
// B=4, S=4096, D=256, fp32 in/out, bf16 MFMA compute.
// Pass 1: fused convert+projection GEMM -> ws (Q scaled by log2e/16; V transposed)
// Pass 2: causal flash attention, 2 waves/block, 16 q-rows/wave, KVB=64.
// ---------------------------------------------------------------------------

typedef __bf16 bf16_t;
typedef bf16_t bf16x8 __attribute__((ext_vector_type(8)));
typedef bf16_t bf16x4 __attribute__((ext_vector_type(4)));
typedef float  f32x4  __attribute__((ext_vector_type(4)));

#define MFMA16(a, b, c) __builtin_amdgcn_mfma_f32_16x16x32_bf16((a), (b), (c), 0, 0, 0)

#define NB      4
#define SEQ     4096
#define DM      256
#define NROWS   (NB * SEQ)          // 16384
#define QSCALE  0.09016844005556021f  // (1/16) * log2(e)

// XOR swizzle: spread rows across 16B bank slots (byte-offset bits 4..6)
__device__ __forceinline__ int swz(int row, int bytecol) {
    return bytecol ^ ((row & 7) << 4);
}

// ---------------------------------------------------------------------------
// Pass 1: projection GEMM.  out[m][n] = sum_k in[m][k] * W[n][k]
// blockIdx.z: 0 -> Q (scaled), 1 -> K, 2 -> V (transposed output Vt[b][d][s])
// Block: 256 thr (4 waves, 2x2), tile 128x128, BK=64.
// ---------------------------------------------------------------------------
__global__ __launch_bounds__(256) void proj_kernel(
    const float* __restrict__ qin, const float* __restrict__ kin,
    const float* __restrict__ vin,
    const float* __restrict__ Wq, const float* __restrict__ Wk,
    const float* __restrict__ Wv,
    bf16_t* __restrict__ Qb, bf16_t* __restrict__ Kb, bf16_t* __restrict__ Vt)
{
    __shared__ char a_lds[128 * 64 * 2];
    __shared__ char w_lds[128 * 64 * 2];

    const int z = blockIdx.z;
    const float* in = (z == 0) ? qin : (z == 1) ? kin : vin;
    const float* W  = (z == 0) ? Wq  : (z == 1) ? Wk  : Wv;

    const int m0 = blockIdx.x * 128;
    const int n0 = blockIdx.y * 128;
    const int tid = threadIdx.x;
    const int l  = tid & 63;
    const int w  = tid >> 6;
    const int wr = w >> 1, wc = w & 1;
    const int lg = l >> 4, cl = l & 15;

    f32x4 acc[4][4] = {};

    for (int k0 = 0; k0 < DM; k0 += 64) {
        // ---- stage A (input rows) and W rows as bf16, swizzled ----
#pragma unroll
        for (int i = 0; i < 8; ++i) {
            int chunk = tid + i * 256;           // 2048 float4 chunks
            int row = chunk >> 4;                // [0,128)
            int kk  = (chunk & 15) * 4;          // [0,64) step 4
            float4 av = *(const float4*)(in + (size_t)(m0 + row) * DM + k0 + kk);
            bf16x4 ap;
            ap[0] = (bf16_t)av.x; ap[1] = (bf16_t)av.y;
            ap[2] = (bf16_t)av.z; ap[3] = (bf16_t)av.w;
            *(bf16x4*)(a_lds + row * 128 + swz(row, kk * 2)) = ap;

            float4 wv4 = *(const float4*)(W + (size_t)(n0 + row) * DM + k0 + kk);
            bf16x4 wp;
            wp[0] = (bf16_t)wv4.x; wp[1] = (bf16_t)wv4.y;
            wp[2] = (bf16_t)wv4.z; wp[3] = (bf16_t)wv4.w;
            *(bf16x4*)(w_lds + row * 128 + swz(row, kk * 2)) = wp;
        }
        __syncthreads();

#pragma unroll
        for (int ks = 0; ks < 2; ++ks) {
            bf16x8 af[4], bfr[4];
#pragma unroll
            for (int mi = 0; mi < 4; ++mi) {
                int row = wr * 64 + mi * 16 + cl;
                int kb2 = (ks * 32 + lg * 8) * 2;
                af[mi] = *(bf16x8*)(a_lds + row * 128 + swz(row, kb2));
            }
#pragma unroll
            for (int ni = 0; ni < 4; ++ni) {
                int row = wc * 64 + ni * 16 + cl;
                int kb2 = (ks * 32 + lg * 8) * 2;
                bfr[ni] = *(bf16x8*)(w_lds + row * 128 + swz(row, kb2));
            }
#pragma unroll
            for (int mi = 0; mi < 4; ++mi)
#pragma unroll
                for (int ni = 0; ni < 4; ++ni)
                    acc[mi][ni] = MFMA16(af[mi], bfr[ni], acc[mi][ni]);
        }
        __syncthreads();
    }

    // ---- epilogue.  C layout: col = lane&15, row = (lane>>4)*4 + i ----
#pragma unroll
    for (int mi = 0; mi < 4; ++mi) {
#pragma unroll
        for (int ni = 0; ni < 4; ++ni) {
            int mbase = m0 + wr * 64 + mi * 16 + lg * 4;
            int ncol  = n0 + wc * 64 + ni * 16 + cl;
            if (z == 0) {
#pragma unroll
                for (int i = 0; i < 4; ++i)
                    Qb[(size_t)(mbase + i) * DM + ncol] = (bf16_t)(acc[mi][ni][i] * QSCALE);
            } else if (z == 1) {
#pragma unroll
                for (int i = 0; i < 4; ++i)
                    Kb[(size_t)(mbase + i) * DM + ncol] = (bf16_t)acc[mi][ni][i];
            } else {
                // V transposed: Vt[b][d=ncol][s], 4 consecutive s -> one 8B store
                int bb = mbase >> 12;
                int s0 = mbase & 4095;
                bf16x4 pk;
                pk[0] = (bf16_t)acc[mi][ni][0]; pk[1] = (bf16_t)acc[mi][ni][1];
                pk[2] = (bf16_t)acc[mi][ni][2]; pk[3] = (bf16_t)acc[mi][ni][3];
                *(bf16x4*)(Vt + ((size_t)bb << 20) + (size_t)ncol * SEQ + s0) = pk;
            }
        }
    }
}

// ---------------------------------------------------------------------------
// Pass 2: causal flash attention.
// 512 blocks x 128 thr (2 waves).  Each wave: 16 q-rows.  KVB = 64.
// Block->chunk map alternates short/long causal extents for balance.
// ---------------------------------------------------------------------------
__global__ __launch_bounds__(128) void attn_kernel(
    const bf16_t* __restrict__ Qb, const bf16_t* __restrict__ Kb,
    const bf16_t* __restrict__ Vt, float* __restrict__ out)
{
    __shared__ __attribute__((aligned(16))) char smem[32768 + 32768 + 2 * 2048];
    char* k_lds = smem;            // [64 rows][256 d] bf16, swizzled
    char* v_lds = smem + 32768;    // [256 d ][64 kv] bf16, swizzled

    const int g = blockIdx.x;
    const int h = ((g & 1) == 0) ? (g >> 1) : (511 - (g >> 1));  // balance map
    const int b = h & 3;
    const int c = h >> 2;                 // 32-row chunk index [0,128)
    const int tid = threadIdx.x;
    const int w = tid >> 6;
    const int l = tid & 63;
    const int lg = l >> 4, cl = l & 15;
    char* p_lds = smem + 65536 + w * 2048;  // per-wave P scratch [16][64] bf16

    const int qbase = c * 32 + w * 16;    // wave's first q row (within batch)
    const int qmax  = qbase + 15;

    // Q fragments: 8 k-steps of bf16x8 (Q pre-scaled by log2e/16)
    const size_t qrow = (size_t)(b * SEQ + qbase + cl);
    bf16x8 qf[8];
#pragma unroll
    for (int ks = 0; ks < 8; ++ks)
        qf[ks] = *(const bf16x8*)(Qb + qrow * DM + ks * 32 + lg * 8);

    f32x4 o[16] = {};
    float m_[4], ssum[4];
#pragma unroll
    for (int i = 0; i < 4; ++i) { m_[i] = -1e30f; ssum[i] = 0.0f; }

    const int E  = c * 32 + 32;           // block kv extent
    const int nt = (E + 63) >> 6;

    for (int t = 0; t < nt; ++t) {
        const int kv0 = t * 64;
        // ---- stage K tile [64][256] ----
#pragma unroll
        for (int i = 0; i < 16; ++i) {
            int chunk = tid + i * 128;
            int row = chunk >> 5;
            int d8  = (chunk & 31) * 8;
            bf16x8 kv = *(const bf16x8*)(Kb + (size_t)(b * SEQ + kv0 + row) * DM + d8);
            *(bf16x8*)(k_lds + row * 512 + swz(row, d8 * 2)) = kv;
        }
        // ---- stage V tile (transposed source) [256][64] ----
#pragma unroll
        for (int i = 0; i < 16; ++i) {
            int chunk = tid + i * 128;
            int dd = chunk >> 3;
            int s8 = (chunk & 7) * 8;
            bf16x8 vv = *(const bf16x8*)(Vt + ((size_t)b << 20) + (size_t)dd * SEQ + kv0 + s8);
            *(bf16x8*)(v_lds + dd * 128 + swz(dd, s8 * 2)) = vv;
        }
        __syncthreads();

        if (kv0 <= qmax) {
            // ---- S = Q K^T (16 x 64), log2 domain ----
            f32x4 sc[4] = {};
#pragma unroll
            for (int ks = 0; ks < 8; ++ks) {
#pragma unroll
                for (int f = 0; f < 4; ++f) {
                    int krow = f * 16 + cl;
                    int kb2  = ks * 64 + lg * 16;
                    bf16x8 kf = *(bf16x8*)(k_lds + krow * 512 + swz(krow, kb2));
                    sc[f] = MFMA16(qf[ks], kf, sc[f]);
                }
            }
            // ---- causal mask ----
            bool fulltile = (kv0 + 63) <= qbase;
            if (!fulltile) {
#pragma unroll
                for (int f = 0; f < 4; ++f)
#pragma unroll
                    for (int i = 0; i < 4; ++i) {
                        int kv = kv0 + f * 16 + cl;
                        int qq = qbase + lg * 4 + i;
                        if (kv > qq) sc[f][i] = -1e30f;
                    }
            }
            // ---- online softmax (per q-row; row spread over 16 lanes) ----
            float al[4];
#pragma unroll
            for (int i = 0; i < 4; ++i) {
                float rm = fmaxf(fmaxf(sc[0][i], sc[1][i]), fmaxf(sc[2][i], sc[3][i]));
#pragma unroll
                for (int off = 1; off < 16; off <<= 1)
                    rm = fmaxf(rm, __shfl_xor(rm, off, 16));
                float mn = fmaxf(m_[i], rm);
                al[i] = exp2f(m_[i] - mn);
                m_[i] = mn;
            }
            float rs[4] = {0.f, 0.f, 0.f, 0.f};
#pragma unroll
            for (int f = 0; f < 4; ++f)
#pragma unroll
                for (int i = 0; i < 4; ++i) {
                    float p = exp2f(sc[f][i] - m_[i]);
                    sc[f][i] = p;
                    rs[i] += p;
                }
#pragma unroll
            for (int i = 0; i < 4; ++i) {
#pragma unroll
                for (int off = 1; off < 16; off <<= 1)
                    rs[i] += __shfl_xor(rs[i], off, 16);
                ssum[i] = ssum[i] * al[i] + rs[i];
            }
#pragma unroll
            for (int n = 0; n < 16; ++n)
#pragma unroll
                for (int i = 0; i < 4; ++i) o[n][i] *= al[i];

            // ---- P -> LDS (transpose C-layout -> A-layout), bf16 ----
#pragma unroll
            for (int f = 0; f < 4; ++f)
#pragma unroll
                for (int i = 0; i < 4; ++i) {
                    int prow = lg * 4 + i;
                    int pcol = f * 16 + cl;
                    *(bf16_t*)(p_lds + prow * 128 + swz(prow, pcol * 2)) = (bf16_t)sc[f][i];
                }
            // ---- O += P V ----
#pragma unroll
            for (int ks2 = 0; ks2 < 2; ++ks2) {
                int pk2 = (ks2 * 32 + lg * 8) * 2;
                bf16x8 pa = *(bf16x8*)(p_lds + cl * 128 + swz(cl, pk2));
#pragma unroll
                for (int n = 0; n < 16; ++n) {
                    int vrow = n * 16 + cl;
                    bf16x8 vf = *(bf16x8*)(v_lds + vrow * 128 + swz(vrow, pk2));
                    o[n] = MFMA16(pa, vf, o[n]);
                }
            }
        }
        __syncthreads();
    }

    // ---- normalize + store fp32 ----
    float inv[4];
#pragma unroll
    for (int i = 0; i < 4; ++i) inv[i] = 1.0f / ssum[i];
#pragma unroll
    for (int n = 0; n < 16; ++n)
#pragma unroll
        for (int i = 0; i < 4; ++i) {
            size_t row = (size_t)(b * SEQ + qbase + lg * 4 + i);
            out[row * DM + n * 16 + cl] = o[n][i] * inv[i];
        }
}

// ---------------------------------------------------------------------------
extern "C" void kernel_launch(void* const* d_in, const int* in_sizes, int n_in,
                              void* d_out, int out_size, void* d_ws, size_t ws_size,
                              hipStream_t stream) {
    const float* k_in = (const float*)d_in[0];
    const float* q_in = (const float*)d_in[1];
    const float* v_in = (const float*)d_in[2];
    const float* Wk   = (const float*)d_in[3];
    const float* Wq   = (const float*)d_in[4];
    const float* Wv   = (const float*)d_in[5];
    // d_in[6] = causal mask (tril) -- implemented analytically.

    bf16_t* Qb = (bf16_t*)d_ws;
    bf16_t* Kb = Qb + (size_t)NROWS * DM;
    bf16_t* Vt = Kb + (size_t)NROWS * DM;
    float* outp = (float*)d_out;

    proj_kernel<<<dim3(NROWS / 128, DM / 128, 3), 256, 0, stream>>>(
        q_in, k_in, v_in, Wq, Wk, Wv, Qb, Kb, Vt);
    attn_kernel<<<512, 128, 0, stream>>>(Qb, Kb, Vt, outp);
}

// Round 2
// 387.294 us; speedup vs baseline: 1.9245x; 1.9245x over previous
//
#include <hip/hip_runtime.h>

// ---------------------------------------------------------------------------
// SingleHeadAttention: out = softmax(mask((q Wq^T)(k Wk^T)^T / 16)) (v Wv^T)
// B=4, S=4096, D=256, fp32 in/out, bf16 MFMA compute.
// Pass 1: fused convert+projection GEMM -> ws (Q scaled by log2e/16; V transposed)
// Pass 2: causal flash attention, 2 waves/block, 16 q-rows/wave, KVB=64.
//         K staged via global_load_lds (dbuf, pre-swizzled source);
//         V fragments read direct from global (L2-resident), no V LDS.
// ---------------------------------------------------------------------------

typedef __bf16 bf16_t;
typedef bf16_t bf16x8 __attribute__((ext_vector_type(8)));
typedef bf16_t bf16x4 __attribute__((ext_vector_type(4)));
typedef float  f32x4  __attribute__((ext_vector_type(4)));

#define MFMA16(a, b, c) __builtin_amdgcn_mfma_f32_16x16x32_bf16((a), (b), (c), 0, 0, 0)

#define GLOAD_LDS16(gsrc, ldst) \
    __builtin_amdgcn_global_load_lds( \
        (const __attribute__((address_space(1))) void*)(gsrc), \
        (__attribute__((address_space(3))) void*)(ldst), 16, 0, 0)

#define NB      4
#define SEQ     4096
#define DM      256
#define NROWS   (NB * SEQ)            // 16384
#define QSCALE  0.09016844005556021f  // (1/16) * log2(e)

// XOR swizzle: spread rows across 16B bank slots (byte-offset bits 4..6)
__device__ __forceinline__ int swz(int row, int bytecol) {
    return bytecol ^ ((row & 7) << 4);
}

// ---------------------------------------------------------------------------
// Pass 1: projection GEMM.  out[m][n] = sum_k in[m][k] * W[n][k]
// blockIdx.z: 0 -> Q (scaled), 1 -> K, 2 -> V (transposed output Vt[b][d][s])
// Block: 256 thr (4 waves, 2x2), tile 128x128, BK=64.
// ---------------------------------------------------------------------------
__global__ __launch_bounds__(256) void proj_kernel(
    const float* __restrict__ qin, const float* __restrict__ kin,
    const float* __restrict__ vin,
    const float* __restrict__ Wq, const float* __restrict__ Wk,
    const float* __restrict__ Wv,
    bf16_t* __restrict__ Qb, bf16_t* __restrict__ Kb, bf16_t* __restrict__ Vt)
{
    __shared__ char a_lds[128 * 64 * 2];
    __shared__ char w_lds[128 * 64 * 2];

    const int z = blockIdx.z;
    const float* in = (z == 0) ? qin : (z == 1) ? kin : vin;
    const float* W  = (z == 0) ? Wq  : (z == 1) ? Wk  : Wv;

    const int m0 = blockIdx.x * 128;
    const int n0 = blockIdx.y * 128;
    const int tid = threadIdx.x;
    const int l  = tid & 63;
    const int w  = tid >> 6;
    const int wr = w >> 1, wc = w & 1;
    const int lg = l >> 4, cl = l & 15;

    f32x4 acc[4][4] = {};

    for (int k0 = 0; k0 < DM; k0 += 64) {
#pragma unroll
        for (int i = 0; i < 8; ++i) {
            int chunk = tid + i * 256;           // 2048 float4 chunks
            int row = chunk >> 4;                // [0,128)
            int kk  = (chunk & 15) * 4;          // [0,64) step 4
            float4 av = *(const float4*)(in + (size_t)(m0 + row) * DM + k0 + kk);
            bf16x4 ap;
            ap[0] = (bf16_t)av.x; ap[1] = (bf16_t)av.y;
            ap[2] = (bf16_t)av.z; ap[3] = (bf16_t)av.w;
            *(bf16x4*)(a_lds + row * 128 + swz(row, kk * 2)) = ap;

            float4 wv4 = *(const float4*)(W + (size_t)(n0 + row) * DM + k0 + kk);
            bf16x4 wp;
            wp[0] = (bf16_t)wv4.x; wp[1] = (bf16_t)wv4.y;
            wp[2] = (bf16_t)wv4.z; wp[3] = (bf16_t)wv4.w;
            *(bf16x4*)(w_lds + row * 128 + swz(row, kk * 2)) = wp;
        }
        __syncthreads();

#pragma unroll
        for (int ks = 0; ks < 2; ++ks) {
            bf16x8 af[4], bfr[4];
#pragma unroll
            for (int mi = 0; mi < 4; ++mi) {
                int row = wr * 64 + mi * 16 + cl;
                int kb2 = (ks * 32 + lg * 8) * 2;
                af[mi] = *(bf16x8*)(a_lds + row * 128 + swz(row, kb2));
            }
#pragma unroll
            for (int ni = 0; ni < 4; ++ni) {
                int row = wc * 64 + ni * 16 + cl;
                int kb2 = (ks * 32 + lg * 8) * 2;
                bfr[ni] = *(bf16x8*)(w_lds + row * 128 + swz(row, kb2));
            }
#pragma unroll
            for (int mi = 0; mi < 4; ++mi)
#pragma unroll
                for (int ni = 0; ni < 4; ++ni)
                    acc[mi][ni] = MFMA16(af[mi], bfr[ni], acc[mi][ni]);
        }
        __syncthreads();
    }

    // ---- epilogue.  C layout: col = lane&15, row = (lane>>4)*4 + i ----
#pragma unroll
    for (int mi = 0; mi < 4; ++mi) {
#pragma unroll
        for (int ni = 0; ni < 4; ++ni) {
            int mbase = m0 + wr * 64 + mi * 16 + lg * 4;
            int ncol  = n0 + wc * 64 + ni * 16 + cl;
            if (z == 0) {
#pragma unroll
                for (int i = 0; i < 4; ++i)
                    Qb[(size_t)(mbase + i) * DM + ncol] = (bf16_t)(acc[mi][ni][i] * QSCALE);
            } else if (z == 1) {
#pragma unroll
                for (int i = 0; i < 4; ++i)
                    Kb[(size_t)(mbase + i) * DM + ncol] = (bf16_t)acc[mi][ni][i];
            } else {
                // V transposed: Vt[b][d=ncol][s], 4 consecutive s -> one 8B store
                int bb = mbase >> 12;
                int s0 = mbase & 4095;
                bf16x4 pk;
                pk[0] = (bf16_t)acc[mi][ni][0]; pk[1] = (bf16_t)acc[mi][ni][1];
                pk[2] = (bf16_t)acc[mi][ni][2]; pk[3] = (bf16_t)acc[mi][ni][3];
                *(bf16x4*)(Vt + ((size_t)bb << 20) + (size_t)ncol * SEQ + s0) = pk;
            }
        }
    }
}

// ---------------------------------------------------------------------------
// Pass 2: causal flash attention.
// 512 blocks x 128 thr (2 waves).  Each wave: 16 q-rows.  KVB = 64.
// K tile [64][256] bf16, double-buffered in LDS via global_load_lds with
// pre-swizzled source addresses (linear LDS dest).  V fragments direct-global.
// ---------------------------------------------------------------------------
__global__ __launch_bounds__(128) void attn_kernel(
    const bf16_t* __restrict__ Qb, const bf16_t* __restrict__ Kb,
    const bf16_t* __restrict__ Vt, float* __restrict__ out)
{
    __shared__ __attribute__((aligned(16))) char smem[65536 + 2 * 2048];

    const int g = blockIdx.x;
    const int h = ((g & 1) == 0) ? (g >> 1) : (511 - (g >> 1));  // balance map
    const int b = h & 3;
    const int c = h >> 2;                 // 32-row chunk index [0,128)
    const int tid = threadIdx.x;
    const int w = tid >> 6;
    const int l = tid & 63;
    const int lg = l >> 4, cl = l & 15;
    char* p_lds = smem + 65536 + w * 2048;  // per-wave P scratch [16][64] bf16
    char* cur = smem;                       // K tile double buffer
    char* nxt = smem + 32768;

    const int qbase = c * 32 + w * 16;    // wave's first q row (within batch)
    const int qmax  = qbase + 15;
    const size_t kvrow0 = (size_t)b * SEQ;

    // Q fragments: 8 k-steps of bf16x8 (Q pre-scaled by log2e/16)
    const size_t qrow = (size_t)(b * SEQ + qbase + cl);
    bf16x8 qf[8];
#pragma unroll
    for (int ks = 0; ks < 8; ++ks)
        qf[ks] = *(const bf16x8*)(Qb + qrow * DM + ks * 32 + lg * 8);

    f32x4 o[16] = {};
    float m_[4], ssum[4];
#pragma unroll
    for (int i = 0; i < 4; ++i) { m_[i] = -1e30f; ssum[i] = 0.0f; }

    const int E  = c * 32 + 32;           // block kv extent
    const int nt = (E + 63) >> 6;

    // ---- prologue: stage K(0) into cur ----
#pragma unroll
    for (int i = 0; i < 16; ++i) {
        int chunk = i * 128 + tid;        // linear 16B chunk in LDS tile
        int row = chunk >> 5;             // [0,64)
        int bc  = (chunk & 31) << 4;      // linear byte col [0,512) step 16
        int scol = bc ^ ((row & 7) << 4); // inverse-swizzled source col
        GLOAD_LDS16(Kb + (kvrow0 + row) * DM + (scol >> 1), cur + chunk * 16);
    }

    for (int t = 0; t < nt; ++t) {
        const int kv0 = t * 64;
        __syncthreads();   // implicit vmcnt(0): K(t) resident in cur; prev reads done

        // ---- issue K(t+1) into nxt (fire-and-forget) ----
        if (t + 1 < nt) {
            const size_t rbase = kvrow0 + (size_t)(t + 1) * 64;
#pragma unroll
            for (int i = 0; i < 16; ++i) {
                int chunk = i * 128 + tid;
                int row = chunk >> 5;
                int bc  = (chunk & 31) << 4;
                int scol = bc ^ ((row & 7) << 4);
                GLOAD_LDS16(Kb + (rbase + row) * DM + (scol >> 1), nxt + chunk * 16);
            }
        }

        if (kv0 <= qmax) {
            // ---- S = Q K^T (16 x 64), log2 domain ----
            f32x4 sc[4] = {};
#pragma unroll
            for (int ks = 0; ks < 8; ++ks) {
#pragma unroll
                for (int f = 0; f < 4; ++f) {
                    int krow = f * 16 + cl;
                    int kb2  = ks * 64 + lg * 16;
                    bf16x8 kf = *(bf16x8*)(cur + krow * 512 + swz(krow, kb2));
                    sc[f] = MFMA16(qf[ks], kf, sc[f]);
                }
            }
            // ---- causal mask ----
            bool fulltile = (kv0 + 63) <= qbase;
            if (!fulltile) {
#pragma unroll
                for (int f = 0; f < 4; ++f)
#pragma unroll
                    for (int i = 0; i < 4; ++i) {
                        int kv = kv0 + f * 16 + cl;
                        int qq = qbase + lg * 4 + i;
                        if (kv > qq) sc[f][i] = -1e30f;
                    }
            }
            // ---- online softmax (per q-row; row spread over 16 lanes) ----
            float al[4];
#pragma unroll
            for (int i = 0; i < 4; ++i) {
                float rm = fmaxf(fmaxf(sc[0][i], sc[1][i]), fmaxf(sc[2][i], sc[3][i]));
#pragma unroll
                for (int off = 1; off < 16; off <<= 1)
                    rm = fmaxf(rm, __shfl_xor(rm, off, 16));
                float mn = fmaxf(m_[i], rm);
                al[i] = exp2f(m_[i] - mn);
                m_[i] = mn;
            }
            float rs[4] = {0.f, 0.f, 0.f, 0.f};
#pragma unroll
            for (int f = 0; f < 4; ++f)
#pragma unroll
                for (int i = 0; i < 4; ++i) {
                    float p = exp2f(sc[f][i] - m_[i]);
                    sc[f][i] = p;
                    rs[i] += p;
                }
#pragma unroll
            for (int i = 0; i < 4; ++i) {
#pragma unroll
                for (int off = 1; off < 16; off <<= 1)
                    rs[i] += __shfl_xor(rs[i], off, 16);
                ssum[i] = ssum[i] * al[i] + rs[i];
            }
#pragma unroll
            for (int n = 0; n < 16; ++n)
#pragma unroll
                for (int i = 0; i < 4; ++i) o[n][i] *= al[i];

            // ---- P -> LDS (transpose C-layout -> A-layout), bf16 ----
#pragma unroll
            for (int f = 0; f < 4; ++f)
#pragma unroll
                for (int i = 0; i < 4; ++i) {
                    int prow = lg * 4 + i;
                    int pcol = f * 16 + cl;
                    *(bf16_t*)(p_lds + prow * 128 + swz(prow, pcol * 2)) = (bf16_t)sc[f][i];
                }
            // ---- O += P V  (V fragments direct from global Vt, 1-deep prefetch)
            bf16x8 pa0 = *(bf16x8*)(p_lds + cl * 128 + swz(cl, lg * 16));
            bf16x8 pa1 = *(bf16x8*)(p_lds + cl * 128 + swz(cl, 64 + lg * 16));
            const bf16_t* vb = Vt + ((size_t)b << 20) + kv0 + lg * 8;
            bf16x8 v0 = *(const bf16x8*)(vb + (size_t)cl * SEQ);
            bf16x8 v1 = *(const bf16x8*)(vb + (size_t)cl * SEQ + 32);
#pragma unroll
            for (int n = 0; n < 16; ++n) {
                bf16x8 nv0, nv1;
                if (n < 15) {
                    nv0 = *(const bf16x8*)(vb + (size_t)((n + 1) * 16 + cl) * SEQ);
                    nv1 = *(const bf16x8*)(vb + (size_t)((n + 1) * 16 + cl) * SEQ + 32);
                }
                o[n] = MFMA16(pa0, v0, o[n]);
                o[n] = MFMA16(pa1, v1, o[n]);
                v0 = nv0; v1 = nv1;
            }
        }
        // swap K double buffers
        char* tmp = cur; cur = nxt; nxt = tmp;
    }

    // ---- normalize + store fp32 ----
    float inv[4];
#pragma unroll
    for (int i = 0; i < 4; ++i) inv[i] = 1.0f / ssum[i];
#pragma unroll
    for (int n = 0; n < 16; ++n)
#pragma unroll
        for (int i = 0; i < 4; ++i) {
            size_t row = (size_t)(b * SEQ + qbase + lg * 4 + i);
            out[row * DM + n * 16 + cl] = o[n][i] * inv[i];
        }
}

// ---------------------------------------------------------------------------
extern "C" void kernel_launch(void* const* d_in, const int* in_sizes, int n_in,
                              void* d_out, int out_size, void* d_ws, size_t ws_size,
                              hipStream_t stream) {
    const float* k_in = (const float*)d_in[0];
    const float* q_in = (const float*)d_in[1];
    const float* v_in = (const float*)d_in[2];
    const float* Wk   = (const float*)d_in[3];
    const float* Wq   = (const float*)d_in[4];
    const float* Wv   = (const float*)d_in[5];
    // d_in[6] = causal mask (tril) -- implemented analytically.

    bf16_t* Qb = (bf16_t*)d_ws;
    bf16_t* Kb = Qb + (size_t)NROWS * DM;
    bf16_t* Vt = Kb + (size_t)NROWS * DM;
    float* outp = (float*)d_out;

    proj_kernel<<<dim3(NROWS / 128, DM / 128, 3), 256, 0, stream>>>(
        q_in, k_in, v_in, Wq, Wk, Wv, Qb, Kb, Vt);
    attn_kernel<<<512, 128, 0, stream>>>(Qb, Kb, Vt, outp);
}

// Round 3
// 232.542 us; speedup vs baseline: 3.2053x; 1.6655x over previous
//
#include <hip/hip_runtime.h>

// ---------------------------------------------------------------------------
// SingleHeadAttention: out = softmax(mask((q Wq^T)(k Wk^T)^T / 16)) (v Wv^T)
// B=4, S=4096, D=256, fp32 in/out, bf16 MFMA compute.
// Pass 1: projection GEMM -> ws (Q scaled by log2e/16; V transposed)
// Pass 2: causal flash attention, KV-split x2.  1024 blocks x 2 waves,
//         16 q-rows/wave, KVB=32, K dbuf via global_load_lds (34 KB LDS ->
//         4 blocks/CU), V fragments all-upfront in registers.
// Pass 3: combine the two kv-halves (m/l rescale) -> d_out.
// ---------------------------------------------------------------------------

typedef __bf16 bf16_t;
typedef bf16_t bf16x8 __attribute__((ext_vector_type(8)));
typedef bf16_t bf16x4 __attribute__((ext_vector_type(4)));
typedef float  f32x4  __attribute__((ext_vector_type(4)));

#define MFMA16(a, b, c) __builtin_amdgcn_mfma_f32_16x16x32_bf16((a), (b), (c), 0, 0, 0)

#define GLOAD_LDS16(gsrc, ldst) \
    __builtin_amdgcn_global_load_lds( \
        (const __attribute__((address_space(1))) void*)(gsrc), \
        (__attribute__((address_space(3))) void*)(ldst), 16, 0, 0)

#define NB      4
#define SEQ     4096
#define DM      256
#define NROWS   (NB * SEQ)            // 16384
#define NELEM   ((size_t)NROWS * DM)  // 4194304
#define QSCALE  0.09016844005556021f  // (1/16) * log2(e)

// XOR swizzle for 512B-row K tiles (16B granularity, bits 4..6)
__device__ __forceinline__ int swz(int row, int bytecol) {
    return bytecol ^ ((row & 7) << 4);
}
// XOR swizzle for 64B-row P tiles (must stay within the row)
__device__ __forceinline__ int swzp(int row, int bytecol) {
    return bytecol ^ ((row & 3) << 4);
}

// ---------------------------------------------------------------------------
// Pass 1: projection GEMM.  out[m][n] = sum_k in[m][k] * W[n][k]
// ---------------------------------------------------------------------------
__global__ __launch_bounds__(256) void proj_kernel(
    const float* __restrict__ qin, const float* __restrict__ kin,
    const float* __restrict__ vin,
    const float* __restrict__ Wq, const float* __restrict__ Wk,
    const float* __restrict__ Wv,
    bf16_t* __restrict__ Qb, bf16_t* __restrict__ Kb, bf16_t* __restrict__ Vt)
{
    __shared__ char a_lds[128 * 64 * 2];
    __shared__ char w_lds[128 * 64 * 2];

    const int z = blockIdx.z;
    const float* in = (z == 0) ? qin : (z == 1) ? kin : vin;
    const float* W  = (z == 0) ? Wq  : (z == 1) ? Wk  : Wv;

    const int m0 = blockIdx.x * 128;
    const int n0 = blockIdx.y * 128;
    const int tid = threadIdx.x;
    const int l  = tid & 63;
    const int w  = tid >> 6;
    const int wr = w >> 1, wc = w & 1;
    const int lg = l >> 4, cl = l & 15;

    f32x4 acc[4][4] = {};

    for (int k0 = 0; k0 < DM; k0 += 64) {
#pragma unroll
        for (int i = 0; i < 8; ++i) {
            int chunk = tid + i * 256;
            int row = chunk >> 4;
            int kk  = (chunk & 15) * 4;
            float4 av = *(const float4*)(in + (size_t)(m0 + row) * DM + k0 + kk);
            bf16x4 ap;
            ap[0] = (bf16_t)av.x; ap[1] = (bf16_t)av.y;
            ap[2] = (bf16_t)av.z; ap[3] = (bf16_t)av.w;
            *(bf16x4*)(a_lds + row * 128 + swz(row, kk * 2)) = ap;

            float4 wv4 = *(const float4*)(W + (size_t)(n0 + row) * DM + k0 + kk);
            bf16x4 wp;
            wp[0] = (bf16_t)wv4.x; wp[1] = (bf16_t)wv4.y;
            wp[2] = (bf16_t)wv4.z; wp[3] = (bf16_t)wv4.w;
            *(bf16x4*)(w_lds + row * 128 + swz(row, kk * 2)) = wp;
        }
        __syncthreads();

#pragma unroll
        for (int ks = 0; ks < 2; ++ks) {
            bf16x8 af[4], bfr[4];
#pragma unroll
            for (int mi = 0; mi < 4; ++mi) {
                int row = wr * 64 + mi * 16 + cl;
                int kb2 = (ks * 32 + lg * 8) * 2;
                af[mi] = *(bf16x8*)(a_lds + row * 128 + swz(row, kb2));
            }
#pragma unroll
            for (int ni = 0; ni < 4; ++ni) {
                int row = wc * 64 + ni * 16 + cl;
                int kb2 = (ks * 32 + lg * 8) * 2;
                bfr[ni] = *(bf16x8*)(w_lds + row * 128 + swz(row, kb2));
            }
#pragma unroll
            for (int mi = 0; mi < 4; ++mi)
#pragma unroll
                for (int ni = 0; ni < 4; ++ni)
                    acc[mi][ni] = MFMA16(af[mi], bfr[ni], acc[mi][ni]);
        }
        __syncthreads();
    }

#pragma unroll
    for (int mi = 0; mi < 4; ++mi) {
#pragma unroll
        for (int ni = 0; ni < 4; ++ni) {
            int mbase = m0 + wr * 64 + mi * 16 + lg * 4;
            int ncol  = n0 + wc * 64 + ni * 16 + cl;
            if (z == 0) {
#pragma unroll
                for (int i = 0; i < 4; ++i)
                    Qb[(size_t)(mbase + i) * DM + ncol] = (bf16_t)(acc[mi][ni][i] * QSCALE);
            } else if (z == 1) {
#pragma unroll
                for (int i = 0; i < 4; ++i)
                    Kb[(size_t)(mbase + i) * DM + ncol] = (bf16_t)acc[mi][ni][i];
            } else {
                int bb = mbase >> 12;
                int s0 = mbase & 4095;
                bf16x4 pk;
                pk[0] = (bf16_t)acc[mi][ni][0]; pk[1] = (bf16_t)acc[mi][ni][1];
                pk[2] = (bf16_t)acc[mi][ni][2]; pk[3] = (bf16_t)acc[mi][ni][3];
                *(bf16x4*)(Vt + ((size_t)bb << 20) + (size_t)ncol * SEQ + s0) = pk;
            }
        }
    }
}

// ---------------------------------------------------------------------------
// Pass 2: causal flash attention with KV-split x2.
// grid 1024:  g -> half = g&1,  (b,c) via balanced map of g>>1.
// Chunk (b,c): q rows [c*32, c*32+32), kv extent E = c*32+32, tiles of 32.
// half0: tiles [0, nh), half1: [nh, nt_all),  nh = nt_all/2.
// Outputs unnormalized O + (m, l) per row per half.
// ---------------------------------------------------------------------------
__global__ __launch_bounds__(128) void attn_kernel(
    const bf16_t* __restrict__ Qb, const bf16_t* __restrict__ Kb,
    const bf16_t* __restrict__ Vt,
    float* __restrict__ O0, bf16_t* __restrict__ O1, float* __restrict__ ML)
{
    __shared__ __attribute__((aligned(16))) char smem[2 * 16384 + 2 * 1024];

    const int g = blockIdx.x;
    const int half = g & 1;
    const int g2 = g >> 1;
    const int h = ((g2 & 1) == 0) ? (g2 >> 1) : (511 - (g2 >> 1));
    const int b = h & 3;
    const int c = h >> 2;                 // 32-row q chunk [0,128)
    const int tid = threadIdx.x;
    const int w = tid >> 6;
    const int l = tid & 63;
    const int lg = l >> 4, cl = l & 15;
    char* p_lds = smem + 32768 + w * 1024;  // per-wave P scratch [16][32] bf16
    char* cur = smem;                       // K tile double buffer [32][256]
    char* nxt = smem + 16384;

    const int qbase = c * 32 + w * 16;
    const size_t kvrow0 = (size_t)b * SEQ;

    const int nt_all = c + 1;             // total 32-kv tiles for this chunk
    const int nh = nt_all >> 1;
    const int t0 = half ? nh : 0;
    const int tN = half ? nt_all : nh;

    // Q fragments
    const size_t qrow = (size_t)(b * SEQ + qbase + cl);
    bf16x8 qf[8];
#pragma unroll
    for (int ks = 0; ks < 8; ++ks)
        qf[ks] = *(const bf16x8*)(Qb + qrow * DM + ks * 32 + lg * 8);

    f32x4 o[16] = {};
    float m_[4], ssum[4];
#pragma unroll
    for (int i = 0; i < 4; ++i) { m_[i] = -1e30f; ssum[i] = 0.0f; }

    // ---- prologue: stage K(t0) ----
    if (t0 < tN) {
#pragma unroll
        for (int i = 0; i < 8; ++i) {
            int chunk = i * 128 + tid;        // 16B chunk in [32][256] tile
            int row = chunk >> 5;             // [0,32)
            int bc  = (chunk & 31) << 4;
            int scol = bc ^ ((row & 7) << 4);
            GLOAD_LDS16(Kb + (kvrow0 + (size_t)t0 * 32 + row) * DM + (scol >> 1),
                        cur + chunk * 16);
        }
    }

    for (int t = t0; t < tN; ++t) {
        const int kv0 = t * 32;
        __syncthreads();   // implicit vmcnt(0): K(t) resident

        if (t + 1 < tN) {
            const size_t rbase = kvrow0 + (size_t)(t + 1) * 32;
#pragma unroll
            for (int i = 0; i < 8; ++i) {
                int chunk = i * 128 + tid;
                int row = chunk >> 5;
                int bc  = (chunk & 31) << 4;
                int scol = bc ^ ((row & 7) << 4);
                GLOAD_LDS16(Kb + (rbase + row) * DM + (scol >> 1), nxt + chunk * 16);
            }
        }

        // ---- V fragments: issue all 16 loads now; consumed after softmax ----
        const bf16_t* vb = Vt + ((size_t)b << 20) + kv0 + lg * 8;
        bf16x8 vf[16];
#pragma unroll
        for (int n = 0; n < 16; ++n)
            vf[n] = *(const bf16x8*)(vb + (size_t)(n * 16 + cl) * SEQ);

        // ---- S = Q K^T (16 x 32), log2 domain ----
        f32x4 sc[2] = {};
#pragma unroll
        for (int ks = 0; ks < 8; ++ks) {
#pragma unroll
            for (int f = 0; f < 2; ++f) {
                int krow = f * 16 + cl;
                int kb2  = ks * 64 + lg * 16;
                bf16x8 kf = *(bf16x8*)(cur + krow * 512 + swz(krow, kb2));
                sc[f] = MFMA16(qf[ks], kf, sc[f]);
            }
        }
        // ---- causal mask (only final tiles need it) ----
        if (kv0 + 31 > qbase) {
#pragma unroll
            for (int f = 0; f < 2; ++f)
#pragma unroll
                for (int i = 0; i < 4; ++i) {
                    int kv = kv0 + f * 16 + cl;
                    int qq = qbase + lg * 4 + i;
                    if (kv > qq) sc[f][i] = -1e30f;
                }
        }
        // ---- online softmax ----
        float al[4];
#pragma unroll
        for (int i = 0; i < 4; ++i) {
            float rm = fmaxf(sc[0][i], sc[1][i]);
#pragma unroll
            for (int off = 1; off < 16; off <<= 1)
                rm = fmaxf(rm, __shfl_xor(rm, off, 16));
            float mn = fmaxf(m_[i], rm);
            al[i] = exp2f(m_[i] - mn);
            m_[i] = mn;
        }
        float rs[4] = {0.f, 0.f, 0.f, 0.f};
#pragma unroll
        for (int f = 0; f < 2; ++f)
#pragma unroll
            for (int i = 0; i < 4; ++i) {
                float p = exp2f(sc[f][i] - m_[i]);
                sc[f][i] = p;
                rs[i] += p;
            }
#pragma unroll
        for (int i = 0; i < 4; ++i) {
#pragma unroll
            for (int off = 1; off < 16; off <<= 1)
                rs[i] += __shfl_xor(rs[i], off, 16);
            ssum[i] = ssum[i] * al[i] + rs[i];
        }
#pragma unroll
        for (int n = 0; n < 16; ++n)
#pragma unroll
            for (int i = 0; i < 4; ++i) o[n][i] *= al[i];

        // ---- P -> LDS (C-layout -> A-layout), bf16 ----
#pragma unroll
        for (int f = 0; f < 2; ++f)
#pragma unroll
            for (int i = 0; i < 4; ++i) {
                int prow = lg * 4 + i;
                int pcol = f * 16 + cl;
                *(bf16_t*)(p_lds + prow * 64 + swzp(prow, pcol * 2)) = (bf16_t)sc[f][i];
            }
        // ---- O += P V ----
        bf16x8 pa = *(bf16x8*)(p_lds + cl * 64 + swzp(cl, lg * 16));
#pragma unroll
        for (int n = 0; n < 16; ++n)
            o[n] = MFMA16(pa, vf[n], o[n]);

        char* tmp = cur; cur = nxt; nxt = tmp;
    }

    // ---- store unnormalized O + (m, l) ----
    if (half == 0) {
#pragma unroll
        for (int n = 0; n < 16; ++n)
#pragma unroll
            for (int i = 0; i < 4; ++i) {
                size_t row = (size_t)(b * SEQ + qbase + lg * 4 + i);
                O0[row * DM + n * 16 + cl] = o[n][i];
            }
    } else {
#pragma unroll
        for (int n = 0; n < 16; ++n)
#pragma unroll
            for (int i = 0; i < 4; ++i) {
                size_t row = (size_t)(b * SEQ + qbase + lg * 4 + i);
                O1[row * DM + n * 16 + cl] = (bf16_t)o[n][i];
            }
    }
    if (cl == 0) {
#pragma unroll
        for (int i = 0; i < 4; ++i) {
            size_t row = (size_t)(b * SEQ + qbase + lg * 4 + i);
            ML[row * 4 + half * 2 + 0] = m_[i];
            ML[row * 4 + half * 2 + 1] = ssum[i];
        }
    }
}

// ---------------------------------------------------------------------------
// Pass 3: combine halves.  out = (w0*O0 + w1*O1) / (w0*l0 + w1*l1)
// ---------------------------------------------------------------------------
__global__ __launch_bounds__(256) void combine_kernel(
    const float* __restrict__ O0, const bf16_t* __restrict__ O1,
    const float* __restrict__ ML, float* __restrict__ out)
{
    const int row = blockIdx.x * 4 + (threadIdx.x >> 6);
    const int l = threadIdx.x & 63;
    const float m0 = ML[row * 4 + 0], l0 = ML[row * 4 + 1];
    const float m1 = ML[row * 4 + 2], l1 = ML[row * 4 + 3];
    const float M  = fmaxf(m0, m1);
    const float w0 = exp2f(m0 - M), w1 = exp2f(m1 - M);
    const float inv = 1.0f / (w0 * l0 + w1 * l1);
    f32x4 a = *(const f32x4*)(O0 + (size_t)row * DM + l * 4);
    bf16x4 bv = *(const bf16x4*)(O1 + (size_t)row * DM + l * 4);
    f32x4 r;
#pragma unroll
    for (int j = 0; j < 4; ++j)
        r[j] = (w0 * a[j] + w1 * (float)bv[j]) * inv;
    *(f32x4*)(out + (size_t)row * DM + l * 4) = r;
}

// ---------------------------------------------------------------------------
extern "C" void kernel_launch(void* const* d_in, const int* in_sizes, int n_in,
                              void* d_out, int out_size, void* d_ws, size_t ws_size,
                              hipStream_t stream) {
    const float* k_in = (const float*)d_in[0];
    const float* q_in = (const float*)d_in[1];
    const float* v_in = (const float*)d_in[2];
    const float* Wk   = (const float*)d_in[3];
    const float* Wq   = (const float*)d_in[4];
    const float* Wv   = (const float*)d_in[5];
    // d_in[6] = causal mask (tril) -- implemented analytically.

    bf16_t* Qb = (bf16_t*)d_ws;
    bf16_t* Kb = Qb + NELEM;
    bf16_t* Vt = Kb + NELEM;
    bf16_t* O1 = Vt + NELEM;              // bf16 partial (half1)
    float*  ML = (float*)(O1 + NELEM);    // [NROWS][2 halves][m,l]
    float* outp = (float*)d_out;          // doubles as half0 partial

    proj_kernel<<<dim3(NROWS / 128, DM / 128, 3), 256, 0, stream>>>(
        q_in, k_in, v_in, Wq, Wk, Wv, Qb, Kb, Vt);
    attn_kernel<<<1024, 128, 0, stream>>>(Qb, Kb, Vt, outp, O1, ML);
    combine_kernel<<<NROWS / 4, 256, 0, stream>>>(outp, O1, ML, outp);
}

// Round 4
// 206.576 us; speedup vs baseline: 3.6082x; 1.1257x over previous
//
#include <hip/hip_runtime.h>

// ---------------------------------------------------------------------------
// SingleHeadAttention: out = softmax(mask((q Wq^T)(k Wk^T)^T / 16)) (v Wv^T)
// B=4, S=4096, D=256, fp32 in/out, bf16 MFMA compute.
// Pass 1: projection GEMM -> ws (Q scaled by log2e/16; V transposed)
// Pass 2: causal flash attention. Balanced blocks: each block handles the
//         chunk pair (p, 127-p) (constant 129 tiles) and 1/SPLIT of each
//         chunk's kv range.  grid = 256*SPLIT blocks x 2 waves, KVB=32,
//         K dbuf via global_load_lds, V fragments all-upfront in registers,
//         defer-max online softmax.  XCD-aware batch mapping.
// Pass 3: combine the SPLIT kv-partials (m/l rescale) -> d_out.
// ---------------------------------------------------------------------------

typedef __bf16 bf16_t;
typedef bf16_t bf16x8 __attribute__((ext_vector_type(8)));
typedef bf16_t bf16x4 __attribute__((ext_vector_type(4)));
typedef float  f32x4  __attribute__((ext_vector_type(4)));

#define MFMA16(a, b, c) __builtin_amdgcn_mfma_f32_16x16x32_bf16((a), (b), (c), 0, 0, 0)

#define GLOAD_LDS16(gsrc, ldst) \
    __builtin_amdgcn_global_load_lds( \
        (const __attribute__((address_space(1))) void*)(gsrc), \
        (__attribute__((address_space(3))) void*)(ldst), 16, 0, 0)

#define NB      4
#define SEQ     4096
#define DM      256
#define NROWS   (NB * SEQ)            // 16384
#define NELEM   ((size_t)NROWS * DM)  // 4194304
#define QSCALE  0.09016844005556021f  // (1/16) * log2(e)
#define DEFER_THR 8.0f                // defer-max threshold (log2 domain)

// XOR swizzle for 512B-row K tiles (16B granularity, bits 4..6)
__device__ __forceinline__ int swz(int row, int bytecol) {
    return bytecol ^ ((row & 7) << 4);
}
// XOR swizzle for 64B-row P tiles (must stay within the row)
__device__ __forceinline__ int swzp(int row, int bytecol) {
    return bytecol ^ ((row & 3) << 4);
}

// ---------------------------------------------------------------------------
// Pass 1: projection GEMM.  out[m][n] = sum_k in[m][k] * W[n][k]
// ---------------------------------------------------------------------------
__global__ __launch_bounds__(256) void proj_kernel(
    const float* __restrict__ qin, const float* __restrict__ kin,
    const float* __restrict__ vin,
    const float* __restrict__ Wq, const float* __restrict__ Wk,
    const float* __restrict__ Wv,
    bf16_t* __restrict__ Qb, bf16_t* __restrict__ Kb, bf16_t* __restrict__ Vt)
{
    __shared__ char a_lds[128 * 64 * 2];
    __shared__ char w_lds[128 * 64 * 2];

    const int z = blockIdx.z;
    const float* in = (z == 0) ? qin : (z == 1) ? kin : vin;
    const float* W  = (z == 0) ? Wq  : (z == 1) ? Wk  : Wv;

    const int m0 = blockIdx.x * 128;
    const int n0 = blockIdx.y * 128;
    const int tid = threadIdx.x;
    const int l  = tid & 63;
    const int w  = tid >> 6;
    const int wr = w >> 1, wc = w & 1;
    const int lg = l >> 4, cl = l & 15;

    f32x4 acc[4][4] = {};

    for (int k0 = 0; k0 < DM; k0 += 64) {
#pragma unroll
        for (int i = 0; i < 8; ++i) {
            int chunk = tid + i * 256;
            int row = chunk >> 4;
            int kk  = (chunk & 15) * 4;
            float4 av = *(const float4*)(in + (size_t)(m0 + row) * DM + k0 + kk);
            bf16x4 ap;
            ap[0] = (bf16_t)av.x; ap[1] = (bf16_t)av.y;
            ap[2] = (bf16_t)av.z; ap[3] = (bf16_t)av.w;
            *(bf16x4*)(a_lds + row * 128 + swz(row, kk * 2)) = ap;

            float4 wv4 = *(const float4*)(W + (size_t)(n0 + row) * DM + k0 + kk);
            bf16x4 wp;
            wp[0] = (bf16_t)wv4.x; wp[1] = (bf16_t)wv4.y;
            wp[2] = (bf16_t)wv4.z; wp[3] = (bf16_t)wv4.w;
            *(bf16x4*)(w_lds + row * 128 + swz(row, kk * 2)) = wp;
        }
        __syncthreads();

#pragma unroll
        for (int ks = 0; ks < 2; ++ks) {
            bf16x8 af[4], bfr[4];
#pragma unroll
            for (int mi = 0; mi < 4; ++mi) {
                int row = wr * 64 + mi * 16 + cl;
                int kb2 = (ks * 32 + lg * 8) * 2;
                af[mi] = *(bf16x8*)(a_lds + row * 128 + swz(row, kb2));
            }
#pragma unroll
            for (int ni = 0; ni < 4; ++ni) {
                int row = wc * 64 + ni * 16 + cl;
                int kb2 = (ks * 32 + lg * 8) * 2;
                bfr[ni] = *(bf16x8*)(w_lds + row * 128 + swz(row, kb2));
            }
#pragma unroll
            for (int mi = 0; mi < 4; ++mi)
#pragma unroll
                for (int ni = 0; ni < 4; ++ni)
                    acc[mi][ni] = MFMA16(af[mi], bfr[ni], acc[mi][ni]);
        }
        __syncthreads();
    }

#pragma unroll
    for (int mi = 0; mi < 4; ++mi) {
#pragma unroll
        for (int ni = 0; ni < 4; ++ni) {
            int mbase = m0 + wr * 64 + mi * 16 + lg * 4;
            int ncol  = n0 + wc * 64 + ni * 16 + cl;
            if (z == 0) {
#pragma unroll
                for (int i = 0; i < 4; ++i)
                    Qb[(size_t)(mbase + i) * DM + ncol] = (bf16_t)(acc[mi][ni][i] * QSCALE);
            } else if (z == 1) {
#pragma unroll
                for (int i = 0; i < 4; ++i)
                    Kb[(size_t)(mbase + i) * DM + ncol] = (bf16_t)acc[mi][ni][i];
            } else {
                int bb = mbase >> 12;
                int s0 = mbase & 4095;
                bf16x4 pk;
                pk[0] = (bf16_t)acc[mi][ni][0]; pk[1] = (bf16_t)acc[mi][ni][1];
                pk[2] = (bf16_t)acc[mi][ni][2]; pk[3] = (bf16_t)acc[mi][ni][3];
                *(bf16x4*)(Vt + ((size_t)bb << 20) + (size_t)ncol * SEQ + s0) = pk;
            }
        }
    }
}

// ---------------------------------------------------------------------------
// Pass 2: causal flash attention, balanced pair + kv-split.
// grid = 256*split.  g -> xcd=g&7, b=xcd>>1, idx=(g>>3)*2+(xcd&1),
// p=idx&63, s=idx>>6.  Block processes chunk p then chunk 127-p, each
// restricted to kv tiles [nt*s/split, nt*(s+1)/split).
// ---------------------------------------------------------------------------
__global__ __launch_bounds__(128) void attn_kernel(
    const bf16_t* __restrict__ Qb, const bf16_t* __restrict__ Kb,
    const bf16_t* __restrict__ Vt,
    float* __restrict__ O0, bf16_t* __restrict__ O1, float* __restrict__ ML,
    int split)
{
    __shared__ __attribute__((aligned(16))) char smem[2 * 16384 + 2 * 1024];

    const int g = blockIdx.x;
    const int xcd = g & 7;
    const int b = xcd >> 1;                       // batch -> 2 XCDs each
    const int idx = ((g >> 3) << 1) | (xcd & 1);  // [0, 64*split)
    const int p = idx & 63;
    const int s = idx >> 6;                       // kv-split slot

    const int tid = threadIdx.x;
    const int w = tid >> 6;
    const int l = tid & 63;
    const int lg = l >> 4, cl = l & 15;
    char* p_lds = smem + 32768 + w * 1024;  // per-wave P scratch [16][32] bf16
    char* cur = smem;                       // K tile double buffer [32][256]
    char* nxt = smem + 16384;

    const size_t kvrow0 = (size_t)b * SEQ;

    const int segc[2] = { p, 127 - p };
    int T0[2], T1[2];
#pragma unroll
    for (int i = 0; i < 2; ++i) {
        int nt = segc[i] + 1;
        T0[i] = (nt * s) / split;
        T1[i] = (nt * (s + 1)) / split;
    }

    auto stageK = [&](int t, char* dst) {
        const size_t rbase = kvrow0 + (size_t)t * 32;
#pragma unroll
        for (int i = 0; i < 8; ++i) {
            int chunk = i * 128 + tid;        // 16B chunk in [32][256] tile
            int row = chunk >> 5;             // [0,32)
            int bc  = (chunk & 31) << 4;
            int scol = bc ^ ((row & 7) << 4); // inverse-swizzled source col
            GLOAD_LDS16(Kb + (rbase + row) * DM + (scol >> 1), dst + chunk * 16);
        }
    };

    // ---- prologue: stage first existing tile ----
    {
        int fsg = (T0[0] < T1[0]) ? 0 : 1;
        if (T0[fsg] < T1[fsg]) stageK(T0[fsg], cur);
    }

    for (int sg = 0; sg < 2; ++sg) {
        const int c = segc[sg];
        const int qbase = c * 32 + w * 16;

        // Q fragments for this segment
        const size_t qrow = (size_t)(b * SEQ + qbase + cl);
        bf16x8 qf[8];
#pragma unroll
        for (int ks = 0; ks < 8; ++ks)
            qf[ks] = *(const bf16x8*)(Qb + qrow * DM + ks * 32 + lg * 8);

        f32x4 o[16] = {};
        float m_[4], ssum[4];
#pragma unroll
        for (int i = 0; i < 4; ++i) { m_[i] = -1e30f; ssum[i] = 0.0f; }

        for (int t = T0[sg]; t < T1[sg]; ++t) {
            const int kv0 = t * 32;
            __syncthreads();   // implicit vmcnt(0): K(t) resident in cur

            // issue next K tile (within segment, or first tile of segment 1)
            if (t + 1 < T1[sg])                       stageK(t + 1, nxt);
            else if (sg == 0 && T0[1] < T1[1])        stageK(T0[1], nxt);

            // ---- V fragments: issue all 16 loads now; consumed after softmax
            const bf16_t* vb = Vt + ((size_t)b << 20) + kv0 + lg * 8;
            bf16x8 vf[16];
#pragma unroll
            for (int n = 0; n < 16; ++n)
                vf[n] = *(const bf16x8*)(vb + (size_t)(n * 16 + cl) * SEQ);

            // ---- S = Q K^T (16 x 32), log2 domain ----
            f32x4 sc[2] = {};
#pragma unroll
            for (int ks = 0; ks < 8; ++ks) {
#pragma unroll
                for (int f = 0; f < 2; ++f) {
                    int krow = f * 16 + cl;
                    int kb2  = ks * 64 + lg * 16;
                    bf16x8 kf = *(bf16x8*)(cur + krow * 512 + swz(krow, kb2));
                    sc[f] = MFMA16(qf[ks], kf, sc[f]);
                }
            }
            // ---- causal mask (only diagonal tiles) ----
            if (kv0 + 31 > qbase) {
#pragma unroll
                for (int f = 0; f < 2; ++f)
#pragma unroll
                    for (int i = 0; i < 4; ++i) {
                        int kv = kv0 + f * 16 + cl;
                        int qq = qbase + lg * 4 + i;
                        if (kv > qq) sc[f][i] = -1e30f;
                    }
            }
            // ---- online softmax with defer-max ----
            float al[4];
#pragma unroll
            for (int i = 0; i < 4; ++i) {
                float rm = fmaxf(sc[0][i], sc[1][i]);
#pragma unroll
                for (int off = 1; off < 16; off <<= 1)
                    rm = fmaxf(rm, __shfl_xor(rm, off, 16));
                // defer small max increases: keep old m, P bounded by 2^THR
                float mn = (rm > m_[i] + DEFER_THR) ? rm : m_[i];
                al[i] = exp2f(m_[i] - mn);   // exactly 1.0 when kept
                m_[i] = mn;
            }
            float rs[4] = {0.f, 0.f, 0.f, 0.f};
#pragma unroll
            for (int f = 0; f < 2; ++f)
#pragma unroll
                for (int i = 0; i < 4; ++i) {
                    float pv = exp2f(sc[f][i] - m_[i]);
                    sc[f][i] = pv;
                    rs[i] += pv;
                }
#pragma unroll
            for (int i = 0; i < 4; ++i) {
#pragma unroll
                for (int off = 1; off < 16; off <<= 1)
                    rs[i] += __shfl_xor(rs[i], off, 16);
                ssum[i] = ssum[i] * al[i] + rs[i];
            }
            if (!(al[0] == 1.0f && al[1] == 1.0f && al[2] == 1.0f && al[3] == 1.0f)) {
#pragma unroll
                for (int n = 0; n < 16; ++n)
#pragma unroll
                    for (int i = 0; i < 4; ++i) o[n][i] *= al[i];
            }

            // ---- P -> LDS (C-layout -> A-layout), bf16 ----
#pragma unroll
            for (int f = 0; f < 2; ++f)
#pragma unroll
                for (int i = 0; i < 4; ++i) {
                    int prow = lg * 4 + i;
                    int pcol = f * 16 + cl;
                    *(bf16_t*)(p_lds + prow * 64 + swzp(prow, pcol * 2)) = (bf16_t)sc[f][i];
                }
            // ---- O += P V ----
            bf16x8 pa = *(bf16x8*)(p_lds + cl * 64 + swzp(cl, lg * 16));
#pragma unroll
            for (int n = 0; n < 16; ++n)
                o[n] = MFMA16(pa, vf[n], o[n]);

            char* tmp = cur; cur = nxt; nxt = tmp;
        }

        // ---- store unnormalized partial O + (m, l) for slot s ----
        if (s == 0) {
#pragma unroll
            for (int n = 0; n < 16; ++n)
#pragma unroll
                for (int i = 0; i < 4; ++i) {
                    size_t row = (size_t)(b * SEQ + qbase + lg * 4 + i);
                    O0[row * DM + n * 16 + cl] = o[n][i];
                }
        } else {
            bf16_t* O1s = O1 + (size_t)(s - 1) * NELEM;
#pragma unroll
            for (int n = 0; n < 16; ++n)
#pragma unroll
                for (int i = 0; i < 4; ++i) {
                    size_t row = (size_t)(b * SEQ + qbase + lg * 4 + i);
                    O1s[row * DM + n * 16 + cl] = (bf16_t)o[n][i];
                }
        }
        if (cl == 0) {
#pragma unroll
            for (int i = 0; i < 4; ++i) {
                size_t row = (size_t)(b * SEQ + qbase + lg * 4 + i);
                ML[(row * split + s) * 2 + 0] = m_[i];
                ML[(row * split + s) * 2 + 1] = ssum[i];
            }
        }
    }
}

// ---------------------------------------------------------------------------
// Pass 3: combine split partials.  out = sum_s w_s O_s / sum_s w_s l_s
// ---------------------------------------------------------------------------
__global__ __launch_bounds__(256) void combine_kernel(
    const float* __restrict__ O0, const bf16_t* __restrict__ O1,
    const float* __restrict__ ML, float* __restrict__ out, int split)
{
    const int row = blockIdx.x * 4 + (threadIdx.x >> 6);
    const int l = threadIdx.x & 63;
    const float* mlr = ML + (size_t)row * split * 2;

    float M = -1e30f;
    for (int s = 0; s < split; ++s) M = fmaxf(M, mlr[s * 2]);
    float denom = 0.0f;
    for (int s = 0; s < split; ++s) denom += exp2f(mlr[s * 2] - M) * mlr[s * 2 + 1];
    const float inv = 1.0f / denom;

    const float w0 = exp2f(mlr[0] - M);
    f32x4 a = *(const f32x4*)(O0 + (size_t)row * DM + l * 4);
    f32x4 acc;
#pragma unroll
    for (int j = 0; j < 4; ++j) acc[j] = w0 * a[j];
    for (int s = 1; s < split; ++s) {
        float wss = exp2f(mlr[s * 2] - M);
        bf16x4 bv = *(const bf16x4*)(O1 + (size_t)(s - 1) * NELEM +
                                     (size_t)row * DM + l * 4);
#pragma unroll
        for (int j = 0; j < 4; ++j) acc[j] += wss * (float)bv[j];
    }
    f32x4 r;
#pragma unroll
    for (int j = 0; j < 4; ++j) r[j] = acc[j] * inv;
    *(f32x4*)(out + (size_t)row * DM + l * 4) = r;
}

// ---------------------------------------------------------------------------
extern "C" void kernel_launch(void* const* d_in, const int* in_sizes, int n_in,
                              void* d_out, int out_size, void* d_ws, size_t ws_size,
                              hipStream_t stream) {
    const float* k_in = (const float*)d_in[0];
    const float* q_in = (const float*)d_in[1];
    const float* v_in = (const float*)d_in[2];
    const float* Wk   = (const float*)d_in[3];
    const float* Wq   = (const float*)d_in[4];
    const float* Wv   = (const float*)d_in[5];
    // d_in[6] = causal mask (tril) -- implemented analytically.

    // ws requirement: Qb,Kb,Vt (3*NELEM bf16) + (split-1)*NELEM bf16 partials
    // + ML (NROWS*split*2 f32)
    const size_t need4 = NELEM * 2 * 6 + (size_t)NROWS * 4 * 2 * sizeof(float);
    const int split = (ws_size >= need4) ? 4 : 2;

    bf16_t* Qb = (bf16_t*)d_ws;
    bf16_t* Kb = Qb + NELEM;
    bf16_t* Vt = Kb + NELEM;
    bf16_t* O1 = Vt + NELEM;                       // (split-1) bf16 partials
    float*  ML = (float*)(O1 + (size_t)(split - 1) * NELEM);
    float* outp = (float*)d_out;                   // doubles as slot-0 partial

    proj_kernel<<<dim3(NROWS / 128, DM / 128, 3), 256, 0, stream>>>(
        q_in, k_in, v_in, Wq, Wk, Wv, Qb, Kb, Vt);
    attn_kernel<<<256 * split, 128, 0, stream>>>(Qb, Kb, Vt, outp, O1, ML, split);
    combine_kernel<<<NROWS / 4, 256, 0, stream>>>(outp, O1, ML, outp, split);
}

// Round 5
// 199.452 us; speedup vs baseline: 3.7370x; 1.0357x over previous
//
#include <hip/hip_runtime.h>

// ---------------------------------------------------------------------------
// SingleHeadAttention: out = softmax(mask((q Wq^T)(k Wk^T)^T / 16)) (v Wv^T)
// B=4, S=4096, D=256, fp32 in/out, bf16 MFMA compute.
// Pass 1: projection GEMM -> ws (Q scaled by log2e/16; V transposed)
// Pass 2: causal flash attention, wave-independent workers:
//         64-thr blocks, 1 wave = 32 q rows, swapped QK^T (mfma32(K,Q)),
//         in-register softmax (1 shfl_xor(32) per reduce), in-register
//         P->PV repack, K/V fragments direct from global, Q in 16KB LDS.
//         Antithetic chunk pair + kv-split for balance. No tile barriers.
// Pass 3: combine the SPLIT kv-partials (m/l rescale) -> d_out.
// ---------------------------------------------------------------------------

typedef __bf16 bf16_t;
typedef bf16_t bf16x8 __attribute__((ext_vector_type(8)));
typedef bf16_t bf16x4 __attribute__((ext_vector_type(4)));
typedef float  f32x4  __attribute__((ext_vector_type(4)));
typedef float  f32x16 __attribute__((ext_vector_type(16)));
typedef unsigned int u32;

#define MFMA16(a, b, c) __builtin_amdgcn_mfma_f32_16x16x32_bf16((a), (b), (c), 0, 0, 0)
#define MFMA32(a, b, c) __builtin_amdgcn_mfma_f32_32x32x16_bf16((a), (b), (c), 0, 0, 0)

#define GLOAD_LDS16(gsrc, ldst) \
    __builtin_amdgcn_global_load_lds( \
        (const __attribute__((address_space(1))) void*)(gsrc), \
        (__attribute__((address_space(3))) void*)(ldst), 16, 0, 0)

#define NB      4
#define SEQ     4096
#define DM      256
#define NROWS   (NB * SEQ)            // 16384
#define NELEM   ((size_t)NROWS * DM)  // 4194304
#define QSCALE  0.09016844005556021f  // (1/16) * log2(e)
#define DEFER_THR 8.0f                // defer-max threshold (log2 domain)

// XOR swizzle for 512B-row tiles (16B granularity)
__device__ __forceinline__ int swz(int row, int bytecol) {
    return bytecol ^ ((row & 7) << 4);
}

__device__ __forceinline__ u32 packbf(float a, float b) {
    union { bf16_t h; unsigned short s; } ca, cb;
    ca.h = (bf16_t)a; cb.h = (bf16_t)b;
    return (u32)ca.s | ((u32)cb.s << 16);
}

typedef u32 u32x4 __attribute__((ext_vector_type(4)));
__device__ __forceinline__ bf16x8 u4_to_b8(u32x4 u) {
    union { u32x4 u; bf16x8 b; } cv; cv.u = u; return cv.b;
}

// ---------------------------------------------------------------------------
// Pass 1: projection GEMM.  out[m][n] = sum_k in[m][k] * W[n][k]
// ---------------------------------------------------------------------------
__global__ __launch_bounds__(256) void proj_kernel(
    const float* __restrict__ qin, const float* __restrict__ kin,
    const float* __restrict__ vin,
    const float* __restrict__ Wq, const float* __restrict__ Wk,
    const float* __restrict__ Wv,
    bf16_t* __restrict__ Qb, bf16_t* __restrict__ Kb, bf16_t* __restrict__ Vt)
{
    __shared__ char a_lds[128 * 64 * 2];
    __shared__ char w_lds[128 * 64 * 2];

    const int z = blockIdx.z;
    const float* in = (z == 0) ? qin : (z == 1) ? kin : vin;
    const float* W  = (z == 0) ? Wq  : (z == 1) ? Wk  : Wv;

    const int m0 = blockIdx.x * 128;
    const int n0 = blockIdx.y * 128;
    const int tid = threadIdx.x;
    const int l  = tid & 63;
    const int w  = tid >> 6;
    const int wr = w >> 1, wc = w & 1;
    const int lg = l >> 4, cl = l & 15;

    f32x4 acc[4][4] = {};

    for (int k0 = 0; k0 < DM; k0 += 64) {
#pragma unroll
        for (int i = 0; i < 8; ++i) {
            int chunk = tid + i * 256;
            int row = chunk >> 4;
            int kk  = (chunk & 15) * 4;
            float4 av = *(const float4*)(in + (size_t)(m0 + row) * DM + k0 + kk);
            bf16x4 ap;
            ap[0] = (bf16_t)av.x; ap[1] = (bf16_t)av.y;
            ap[2] = (bf16_t)av.z; ap[3] = (bf16_t)av.w;
            *(bf16x4*)(a_lds + row * 128 + swz(row, kk * 2)) = ap;

            float4 wv4 = *(const float4*)(W + (size_t)(n0 + row) * DM + k0 + kk);
            bf16x4 wp;
            wp[0] = (bf16_t)wv4.x; wp[1] = (bf16_t)wv4.y;
            wp[2] = (bf16_t)wv4.z; wp[3] = (bf16_t)wv4.w;
            *(bf16x4*)(w_lds + row * 128 + swz(row, kk * 2)) = wp;
        }
        __syncthreads();

#pragma unroll
        for (int ks = 0; ks < 2; ++ks) {
            bf16x8 af[4], bfr[4];
#pragma unroll
            for (int mi = 0; mi < 4; ++mi) {
                int row = wr * 64 + mi * 16 + cl;
                int kb2 = (ks * 32 + lg * 8) * 2;
                af[mi] = *(bf16x8*)(a_lds + row * 128 + swz(row, kb2));
            }
#pragma unroll
            for (int ni = 0; ni < 4; ++ni) {
                int row = wc * 64 + ni * 16 + cl;
                int kb2 = (ks * 32 + lg * 8) * 2;
                bfr[ni] = *(bf16x8*)(w_lds + row * 128 + swz(row, kb2));
            }
#pragma unroll
            for (int mi = 0; mi < 4; ++mi)
#pragma unroll
                for (int ni = 0; ni < 4; ++ni)
                    acc[mi][ni] = MFMA16(af[mi], bfr[ni], acc[mi][ni]);
        }
        __syncthreads();
    }

#pragma unroll
    for (int mi = 0; mi < 4; ++mi) {
#pragma unroll
        for (int ni = 0; ni < 4; ++ni) {
            int mbase = m0 + wr * 64 + mi * 16 + lg * 4;
            int ncol  = n0 + wc * 64 + ni * 16 + cl;
            if (z == 0) {
#pragma unroll
                for (int i = 0; i < 4; ++i)
                    Qb[(size_t)(mbase + i) * DM + ncol] = (bf16_t)(acc[mi][ni][i] * QSCALE);
            } else if (z == 1) {
#pragma unroll
                for (int i = 0; i < 4; ++i)
                    Kb[(size_t)(mbase + i) * DM + ncol] = (bf16_t)acc[mi][ni][i];
            } else {
                int bb = mbase >> 12;
                int s0 = mbase & 4095;
                bf16x4 pk;
                pk[0] = (bf16_t)acc[mi][ni][0]; pk[1] = (bf16_t)acc[mi][ni][1];
                pk[2] = (bf16_t)acc[mi][ni][2]; pk[3] = (bf16_t)acc[mi][ni][3];
                *(bf16x4*)(Vt + ((size_t)bb << 20) + (size_t)ncol * SEQ + s0) = pk;
            }
        }
    }
}

// ---------------------------------------------------------------------------
// Pass 2: wave-independent causal flash attention (swapped QK^T, 32x32).
// grid = 256*split, 64 thr.  g -> xcd=g&7, b=xcd>>1, idx=(g>>3)*2+(xcd&1),
// p=idx&63, s=idx>>6.  Segments c=p and c=127-p (32-row chunks); kv tiles
// [nt*s/split, nt*(s+1)/split), nt=c+1, KVB=32.
//
// Layouts (mfma_f32_32x32x16_bf16):
//   A: lane l -> row=l&31, k=(l>>5)*8+j ;  B: col=l&31, k=(l>>5)*8+j
//   C: col=l&31, row=(r&3)+8*(r>>2)+4*(l>>5)
// QK^T: S[kv][q] = mfma(A=K rows, B=Q cols).  Lane owns P column for q=l&31.
// PV:   O^T[d][q] = mfma(A=Vt rows, B=P^T cols), P^T built via pack+shfl32.
// ---------------------------------------------------------------------------
__global__ __launch_bounds__(64, 2) void attn_kernel(
    const bf16_t* __restrict__ Qb, const bf16_t* __restrict__ Kb,
    const bf16_t* __restrict__ Vt,
    float* __restrict__ O0, bf16_t* __restrict__ O1, float* __restrict__ ML,
    int split)
{
    __shared__ __attribute__((aligned(16))) char q_lds[16384];  // [32][256] bf16 swz16

    const int g = blockIdx.x;
    const int xcd = g & 7;
    const int b = xcd >> 1;
    const int idx = ((g >> 3) << 1) | (xcd & 1);
    const int p = idx & 63;
    const int s = idx >> 6;

    const int l  = threadIdx.x & 63;
    const int q5 = l & 31;          // q col (QK^T/PV C), kv row (K A), d row (V A)
    const int hi = l >> 5;

    const int segc[2] = { p, 127 - p };

    for (int sg = 0; sg < 2; ++sg) {
        const int c = segc[sg];
        const int qbase = c * 32;
        const int nt = c + 1;
        const int T0 = (nt * s) / split;
        const int T1 = (nt * (s + 1)) / split;
        const int qg = qbase + q5;   // this lane's q row (within batch)

        if (T0 < T1) {
            // ---- stage Q [32][256] -> LDS, swz16, pre-swizzled source ----
            __syncthreads();
            const size_t qr0 = (size_t)(b * SEQ + qbase);
#pragma unroll
            for (int i = 0; i < 16; ++i) {
                int chunk = i * 64 + l;
                int row = chunk >> 5;
                int bc  = (chunk & 31) << 4;
                int scol = bc ^ ((row & 15) << 4);
                GLOAD_LDS16(Qb + (qr0 + row) * DM + (scol >> 1), q_lds + chunk * 16);
            }
            __syncthreads();
        }

        f32x16 o[8] = {};
        float m_ = -1e30f, ssum = 0.0f;

        for (int t = T0; t < T1; ++t) {
            const int kv0 = t * 32;

            // ---- S^T = K Q^T : S[kv][q], two acc chains ----
            const bf16_t* kb = Kb + (size_t)(b * SEQ + kv0 + q5) * DM + hi * 8;
            f32x16 sA = {}, sB = {};
#pragma unroll
            for (int ks = 0; ks < 16; ++ks) {
                bf16x8 kf = *(const bf16x8*)(kb + ks * 16);
                int bcol = 32 * ks + 16 * hi;
                bf16x8 qf = *(const bf16x8*)(q_lds + q5 * 512 +
                                             (bcol ^ ((q5 & 15) << 4)));
                if (ks & 1) sB = MFMA32(kf, qf, sB);
                else        sA = MFMA32(kf, qf, sA);
            }
            f32x16 sv = sA + sB;

            // ---- causal mask (diagonal tile only) ----
            if (t == c) {
#pragma unroll
                for (int r = 0; r < 16; ++r) {
                    int kv = kv0 + (r & 3) + 8 * (r >> 2) + 4 * hi;
                    if (kv > qg) sv[r] = -1e30f;
                }
            }

            // ---- online softmax, lane-local + one shfl ----
            float rm = sv[0];
#pragma unroll
            for (int r = 1; r < 16; ++r) rm = fmaxf(rm, sv[r]);
            rm = fmaxf(rm, __shfl_xor(rm, 32));
            float mn = (rm > m_ + DEFER_THR) ? rm : m_;
            float al = exp2f(m_ - mn);
            m_ = mn;
            float rs = 0.0f;
#pragma unroll
            for (int r = 0; r < 16; ++r) { sv[r] = exp2f(sv[r] - mn); rs += sv[r]; }
            rs += __shfl_xor(rs, 32);
            ssum = ssum * al + rs;
            if (al != 1.0f) {
#pragma unroll
                for (int db = 0; db < 8; ++db) o[db] *= al;
            }

            // ---- P^T -> bf16 B-fragments (pack + shfl32 + select) ----
            u32 cpk[8], spk[8];
#pragma unroll
            for (int j = 0; j < 8; ++j) cpk[j] = packbf(sv[2 * j], sv[2 * j + 1]);
#pragma unroll
            for (int j = 0; j < 8; ++j) spk[j] = (u32)__shfl_xor((int)cpk[j], 32);
            u32x4 f0, f1;
            f0[0] = hi ? spk[2] : cpk[0];
            f0[1] = hi ? spk[3] : cpk[1];
            f0[2] = hi ? cpk[2] : spk[0];
            f0[3] = hi ? cpk[3] : spk[1];
            f1[0] = hi ? spk[6] : cpk[4];
            f1[1] = hi ? spk[7] : cpk[5];
            f1[2] = hi ? cpk[6] : spk[4];
            f1[3] = hi ? cpk[7] : spk[5];
            bf16x8 pb0 = u4_to_b8(f0);
            bf16x8 pb1 = u4_to_b8(f1);

            // ---- O^T += Vt P^T ----
            const bf16_t* vbase = Vt + ((size_t)b << 20) + kv0 + hi * 8;
#pragma unroll
            for (int db = 0; db < 8; ++db) {
                const bf16_t* vr = vbase + (size_t)(db * 32 + q5) * SEQ;
                bf16x8 v0 = *(const bf16x8*)(vr);
                bf16x8 v1 = *(const bf16x8*)(vr + 16);
                o[db] = MFMA32(v0, pb0, o[db]);
                o[db] = MFMA32(v1, pb1, o[db]);
            }
        }

        // ---- store partial O^T (lane q row is contiguous in d) + (m,l) ----
        const size_t row = (size_t)(b * SEQ + qg);
        if (s == 0) {
#pragma unroll
            for (int db = 0; db < 8; ++db)
#pragma unroll
                for (int rr = 0; rr < 4; ++rr) {
                    int d = db * 32 + rr * 8 + hi * 4;
                    f32x4 v4 = { o[db][rr * 4 + 0], o[db][rr * 4 + 1],
                                 o[db][rr * 4 + 2], o[db][rr * 4 + 3] };
                    *(f32x4*)(O0 + row * DM + d) = v4;
                }
        } else {
            bf16_t* O1s = O1 + (size_t)(s - 1) * NELEM;
#pragma unroll
            for (int db = 0; db < 8; ++db)
#pragma unroll
                for (int rr = 0; rr < 4; ++rr) {
                    int d = db * 32 + rr * 8 + hi * 4;
                    bf16x4 v4;
                    v4[0] = (bf16_t)o[db][rr * 4 + 0];
                    v4[1] = (bf16_t)o[db][rr * 4 + 1];
                    v4[2] = (bf16_t)o[db][rr * 4 + 2];
                    v4[3] = (bf16_t)o[db][rr * 4 + 3];
                    *(bf16x4*)(O1s + row * DM + d) = v4;
                }
        }
        if (hi == 0) {
            ML[(row * split + s) * 2 + 0] = m_;
            ML[(row * split + s) * 2 + 1] = ssum;
        }
    }
}

// ---------------------------------------------------------------------------
// Pass 3: combine split partials.  out = sum_s w_s O_s / sum_s w_s l_s
// ---------------------------------------------------------------------------
__global__ __launch_bounds__(256) void combine_kernel(
    const float* __restrict__ O0, const bf16_t* __restrict__ O1,
    const float* __restrict__ ML, float* __restrict__ out, int split)
{
    const int row = blockIdx.x * 4 + (threadIdx.x >> 6);
    const int l = threadIdx.x & 63;
    const float* mlr = ML + (size_t)row * split * 2;

    float M = -1e30f;
    for (int s = 0; s < split; ++s) M = fmaxf(M, mlr[s * 2]);
    float denom = 0.0f;
    for (int s = 0; s < split; ++s) denom += exp2f(mlr[s * 2] - M) * mlr[s * 2 + 1];
    const float inv = 1.0f / denom;

    const float w0 = exp2f(mlr[0] - M);
    f32x4 a = *(const f32x4*)(O0 + (size_t)row * DM + l * 4);
    f32x4 acc;
#pragma unroll
    for (int j = 0; j < 4; ++j) acc[j] = w0 * a[j];
    for (int s = 1; s < split; ++s) {
        float wss = exp2f(mlr[s * 2] - M);
        bf16x4 bv = *(const bf16x4*)(O1 + (size_t)(s - 1) * NELEM +
                                     (size_t)row * DM + l * 4);
#pragma unroll
        for (int j = 0; j < 4; ++j) acc[j] += wss * (float)bv[j];
    }
    f32x4 r;
#pragma unroll
    for (int j = 0; j < 4; ++j) r[j] = acc[j] * inv;
    *(f32x4*)(out + (size_t)row * DM + l * 4) = r;
}

// ---------------------------------------------------------------------------
extern "C" void kernel_launch(void* const* d_in, const int* in_sizes, int n_in,
                              void* d_out, int out_size, void* d_ws, size_t ws_size,
                              hipStream_t stream) {
    const float* k_in = (const float*)d_in[0];
    const float* q_in = (const float*)d_in[1];
    const float* v_in = (const float*)d_in[2];
    const float* Wk   = (const float*)d_in[3];
    const float* Wq   = (const float*)d_in[4];
    const float* Wv   = (const float*)d_in[5];
    // d_in[6] = causal mask (tril) -- implemented analytically.

    // ws: Qb,Kb,Vt (3*NELEM bf16) + (split-1)*NELEM bf16 partials + ML
    const size_t need8 = NELEM * 2 * 10 + (size_t)NROWS * 8 * 2 * sizeof(float);
    const size_t need4 = NELEM * 2 * 6  + (size_t)NROWS * 4 * 2 * sizeof(float);
    const int split = (ws_size >= need8) ? 8 : (ws_size >= need4) ? 4 : 2;

    bf16_t* Qb = (bf16_t*)d_ws;
    bf16_t* Kb = Qb + NELEM;
    bf16_t* Vt = Kb + NELEM;
    bf16_t* O1 = Vt + NELEM;
    float*  ML = (float*)(O1 + (size_t)(split - 1) * NELEM);
    float* outp = (float*)d_out;                   // doubles as slot-0 partial

    proj_kernel<<<dim3(NROWS / 128, DM / 128, 3), 256, 0, stream>>>(
        q_in, k_in, v_in, Wq, Wk, Wv, Qb, Kb, Vt);
    attn_kernel<<<256 * split, 64, 0, stream>>>(Qb, Kb, Vt, outp, O1, ML, split);
    combine_kernel<<<NROWS / 4, 256, 0, stream>>>(outp, O1, ML, outp, split);
}